// Round 2
// baseline (168.652 us; speedup 1.0000x reference)
//
#include <hip/hip_runtime.h>
#include <hip/hip_fp16.h>
#include <math.h>

#define DIM 128
#define NVOX (DIM*DIM*DIM)

// clang native vector types (HIP's float4/uint4 are classes — rejected by
// __builtin_nontemporal_load/store)
typedef float vfloat4 __attribute__((ext_vector_type(4)));
typedef unsigned int vuint4 __attribute__((ext_vector_type(4)));
typedef unsigned int vuint3 __attribute__((ext_vector_type(3)));  // sizeof==16
static_assert(sizeof(vuint3) == 16, "vuint3 must stride 16B over the AoS array");

// ---------------- Pass A: dti (6,NVOX) f32 SoA -> AoS fp16 16B/voxel ---------
// One warp corner = one global_load touching ONE cache line instead of
// 6 scalar loads into 6 separate 8MB planes (R4: L1-transaction-bound).
// 4 voxels/thread, nt loads (dti is dead after this pass; keep it out of
// L2/L3 so the aos array stays resident). Same XCD swizzle as pass B so each
// slab is written by the XCD that will gather from it.
__global__ __launch_bounds__(256) void pack_dti_kernel(
    const float* __restrict__ dti, vuint4* __restrict__ aos)
{
    const int bid = blockIdx.x;                    // 2048 blocks
    const int sb = ((bid & 7) << 8) | (bid >> 3);  // XCD i-slab swizzle
    const int id4 = (sb * 256 + (int)threadIdx.x) * 4;

    const vfloat4 v0 = __builtin_nontemporal_load(reinterpret_cast<const vfloat4*>(dti + 0 * NVOX + id4));
    const vfloat4 v1 = __builtin_nontemporal_load(reinterpret_cast<const vfloat4*>(dti + 1 * NVOX + id4));
    const vfloat4 v2 = __builtin_nontemporal_load(reinterpret_cast<const vfloat4*>(dti + 2 * NVOX + id4));
    const vfloat4 v3 = __builtin_nontemporal_load(reinterpret_cast<const vfloat4*>(dti + 3 * NVOX + id4));
    const vfloat4 v4 = __builtin_nontemporal_load(reinterpret_cast<const vfloat4*>(dti + 4 * NVOX + id4));
    const vfloat4 v5 = __builtin_nontemporal_load(reinterpret_cast<const vfloat4*>(dti + 5 * NVOX + id4));

    auto packone = [&](float a0, float a1, float a2, float a3, float a4,
                       float a5, int idx) {
        const __half2 h01 = __floats2half2_rn(a0, a1);
        const __half2 h23 = __floats2half2_rn(a2, a3);
        const __half2 h45 = __floats2half2_rn(a4, a5);
        vuint4 q;
        q.x = *reinterpret_cast<const unsigned int*>(&h01);
        q.y = *reinterpret_cast<const unsigned int*>(&h23);
        q.z = *reinterpret_cast<const unsigned int*>(&h45);
        q.w = 0u;
        aos[idx] = q;  // normal store: we WANT these lines in L2 for pass B
    };
    packone(v0.x, v1.x, v2.x, v3.x, v4.x, v5.x, id4 + 0);
    packone(v0.y, v1.y, v2.y, v3.y, v4.y, v5.y, id4 + 1);
    packone(v0.z, v1.z, v2.z, v3.z, v4.z, v5.z, id4 + 2);
    packone(v0.w, v1.w, v2.w, v3.w, v4.w, v5.w, id4 + 3);
}

// ---- fp32 polar factor: branch-free 3 scaled + 2 unscaled Newton ------------
// Fixed point: R = U @ Vh (SVD polar factor), sign(det) preserved.
// For cond<=2e3: scaled iters contract sigma-range 22 -> 2.5 -> 1.1, then
// unscaled e^2/2: 0.1 -> 5e-3 -> 1.3e-5 (orthogonality error; output
// perturbation ~1e-4 << fp16-pack absmax 0.0156, so the 6th iter was waste).
// Returns bad=true for cond_F(J) > 2e3 (caller redoes in fp64).
__device__ __forceinline__ bool polar_f32(const float J[9], float X[9])
{
#pragma unroll
    for (int t = 0; t < 9; ++t) X[t] = J[t];
    bool bad = false;
#pragma unroll
    for (int it = 0; it < 5; ++it) {
        float C[9];
        C[0] = X[4] * X[8] - X[5] * X[7];
        C[1] = X[5] * X[6] - X[3] * X[8];
        C[2] = X[3] * X[7] - X[4] * X[6];
        C[3] = X[2] * X[7] - X[1] * X[8];
        C[4] = X[0] * X[8] - X[2] * X[6];
        C[5] = X[1] * X[6] - X[0] * X[7];
        C[6] = X[1] * X[5] - X[2] * X[4];
        C[7] = X[2] * X[3] - X[0] * X[5];
        C[8] = X[0] * X[4] - X[1] * X[3];
        const float det = X[0] * C[0] + X[1] * C[1] + X[2] * C[2];
        float a, b;
        if (it < 3) {
            float nX = 0.0f, nC = 0.0f;
#pragma unroll
            for (int t = 0; t < 9; ++t) { nX += X[t] * X[t]; nC += C[t] * C[t]; }
            if (it == 0)
                bad = !(nX * nC < 4.0e6f * det * det);  // condF > 2e3 (sqrt-free)
            // s = ||C||/||X||; r = 1/sqrt(s*|det|); a = 0.5*s*r = 0.5*g;
            // b = 0.5*r*sign(det)  (g = sqrt(s/|det|), b = 0.5/(g*det))
            const float s = __builtin_amdgcn_sqrtf(nC * __builtin_amdgcn_rcpf(nX));
            const float r = __builtin_amdgcn_rsqf(s * fabsf(det));
            a = 0.5f * s * r;
            b = copysignf(0.5f * r, det);
        } else {
            a = 0.5f;
            b = 0.5f * __builtin_amdgcn_rcpf(det);
        }
#pragma unroll
        for (int t = 0; t < 9; ++t) X[t] = a * X[t] + b * C[t];
    }
    return bad;
}

// ---- fp64 fallback (rare; inline & unrolled => register-resident; a
// noinline call made these arrays addressable -> ~220MB scratch spill in R2) --
__device__ __forceinline__ void polar_f64(const float J[9], float X[9])
{
    double Y[9];
#pragma unroll
    for (int t = 0; t < 9; ++t) Y[t] = (double)J[t];
    for (int it = 0; it < 20; ++it) {
        double C[9];
        C[0] = Y[4] * Y[8] - Y[5] * Y[7];
        C[1] = Y[5] * Y[6] - Y[3] * Y[8];
        C[2] = Y[3] * Y[7] - Y[4] * Y[6];
        C[3] = Y[2] * Y[7] - Y[1] * Y[8];
        C[4] = Y[0] * Y[8] - Y[2] * Y[6];
        C[5] = Y[1] * Y[6] - Y[0] * Y[7];
        C[6] = Y[1] * Y[5] - Y[2] * Y[4];
        C[7] = Y[2] * Y[3] - Y[0] * Y[5];
        C[8] = Y[0] * Y[4] - Y[1] * Y[3];
        const double det = Y[0] * C[0] + Y[1] * C[1] + Y[2] * C[2];
        if (!(fabs(det) > 1e-300)) break;
        double nX = 0.0, nC = 0.0;
#pragma unroll
        for (int t = 0; t < 9; ++t) { nX += Y[t] * Y[t]; nC += C[t] * C[t]; }
        const double g = sqrt(sqrt(nC) / (fabs(det) * sqrt(nX)));
        const double a = 0.5 * g;
        const double b = 0.5 / (g * det);
        double diff2 = 0.0, n2 = 0.0;
#pragma unroll
        for (int t = 0; t < 9; ++t) {
            const double y = a * Y[t] + b * C[t];
            const double d = y - Y[t];
            diff2 += d * d; n2 += y * y;
            Y[t] = y;
        }
        if (diff2 <= 1e-26 * n2) break;
    }
#pragma unroll
    for (int t = 0; t < 9; ++t) X[t] = (float)Y[t];
}

// ---------------- Pass B: warp + polar + congruence --------------------------
// R6 restructure: software-pipeline within the thread. All 29 global loads
// (3 ddf@id -> 18 ddf neighbors -> 8 aos gathers) are ISSUED before any
// long-latency consumption; the ~300-instr pure-VALU polar iteration runs
// while the gathers (L2/L3, ~300-700cy) are in flight; the first vmcnt(0)
// lands at the interp accumulation AFTER polar. Gathers held as dwordx3
// (12 of 16 B used) = 24 VGPRs. fp64 fallback moved after accumulation so
// those 24 regs are dead before the register-hungry f64 path.
__global__ __launch_bounds__(256) void warp_dti_kernel(
    const vuint3* __restrict__ aos,
    const float* __restrict__ ddf,
    float* __restrict__ out)
{
    const int bid = blockIdx.x;                     // 8192 blocks
    const int sb = ((bid & 7) << 10) | (bid >> 3);  // XCD i-slab swizzle
    const int id = sb * 256 + (int)threadIdx.x;
    const int k = id & (DIM - 1);
    const int j = (id >> 7) & (DIM - 1);
    const int i = id >> 14;

    // ---- displacement loads FIRST: they gate the gather addresses ----
    const float* __restrict__ p0_ = ddf;
    const float* __restrict__ p1_ = ddf + NVOX;
    const float* __restrict__ p2_ = ddf + 2 * NVOX;
    const float u0 = p0_[id];
    const float u1 = p1_[id];
    const float u2 = p2_[id];

    // ---- Jacobian neighbor addresses + issue all 18 loads ----
    const int im = (i > 0) ? i - 1 : 0, ip = (i < DIM - 1) ? i + 1 : DIM - 1;
    const int jm = (j > 0) ? j - 1 : 0, jp = (j < DIM - 1) ? j + 1 : DIM - 1;
    const int km = (k > 0) ? k - 1 : 0, kp = (k < DIM - 1) ? k + 1 : DIM - 1;
    const float si = (ip - im == 2) ? 0.5f : 1.0f;
    const float sj = (jp - jm == 2) ? 0.5f : 1.0f;
    const float sk = (kp - km == 2) ? 0.5f : 1.0f;

    const int l_ip = (ip << 14) | (j << 7) | k;
    const int l_im = (im << 14) | (j << 7) | k;
    const int l_jp = (i << 14) | (jp << 7) | k;
    const int l_jm = (i << 14) | (jm << 7) | k;
    const int l_kp = (i << 14) | (j << 7) | kp;
    const int l_km = (i << 14) | (j << 7) | km;

    const float n0a = p0_[l_ip], n0b = p0_[l_im], n0c = p0_[l_jp];
    const float n0d = p0_[l_jm], n0e = p0_[l_kp], n0f = p0_[l_km];
    const float n1a = p1_[l_ip], n1b = p1_[l_im], n1c = p1_[l_jp];
    const float n1d = p1_[l_jm], n1e = p1_[l_kp], n1f = p1_[l_km];
    const float n2a = p2_[l_ip], n2b = p2_[l_im], n2c = p2_[l_jp];
    const float n2d = p2_[l_jm], n2e = p2_[l_kp], n2f = p2_[l_km];

    // ---- Trilinear gather setup (depends only on u*, border padding) ----
    const float cx = fminf(fmaxf((float)i + u0, 0.0f), (float)(DIM - 1));
    const float cy = fminf(fmaxf((float)j + u1, 0.0f), (float)(DIM - 1));
    const float cz = fminf(fmaxf((float)k + u2, 0.0f), (float)(DIM - 1));
    const float x0f = floorf(cx), y0f = floorf(cy), z0f = floorf(cz);
    const float fx = cx - x0f, fy = cy - y0f, fz = cz - z0f;
    const int x0 = (int)x0f, y0 = (int)y0f, z0 = (int)z0f;
    const int x1 = min(x0 + 1, DIM - 1);
    const int y1 = min(y0 + 1, DIM - 1);
    const int z1 = min(z0 + 1, DIM - 1);

    // delta addressing: corners = base + {0,dz} + {0,dy} + {0,dx}
    const int dz = z1 - z0;
    const int dy = (y1 - y0) << 7;
    const int dx = (x1 - x0) << 14;
    const int b000 = (x0 << 14) | (y0 << 7) | z0;

    // ---- issue all 8 gathers NOW; consumed after polar (latency hidden) ----
    const vuint3 q0 = aos[b000];
    const vuint3 q1 = aos[b000 + dz];
    const vuint3 q2 = aos[b000 + dy];
    const vuint3 q3 = aos[b000 + dy + dz];
    const vuint3 q4 = aos[b000 + dx];
    const vuint3 q5 = aos[b000 + dx + dz];
    const vuint3 q6 = aos[b000 + dx + dy];
    const vuint3 q7 = aos[b000 + dx + dy + dz];

    // ---- Jacobian: J = I + grad(ddf) (waits neighbor loads only) ----
    float J[9];
    J[0] = (n0a - n0b) * si + 1.0f;
    J[1] = (n0c - n0d) * sj;
    J[2] = (n0e - n0f) * sk;
    J[3] = (n1a - n1b) * si;
    J[4] = (n1c - n1d) * sj + 1.0f;
    J[5] = (n1e - n1f) * sk;
    J[6] = (n2a - n2b) * si;
    J[7] = (n2c - n2d) * sj;
    J[8] = (n2e - n2f) * sk + 1.0f;

    // ---- Polar factor: long pure-VALU stretch, gathers in flight ----
    float X[9];
    const bool bad = polar_f32(J, X);

    // ---- interp accumulate (first vmcnt wait on the gathers is here) ----
    const float gx0 = 1.0f - fx, gy0 = 1.0f - fy, gz0 = 1.0f - fz;
    float acc0 = 0.0f, acc1 = 0.0f, acc2 = 0.0f;
    float acc3 = 0.0f, acc4 = 0.0f, acc5 = 0.0f;

    // fmaf((float)half, wt, acc) folds to v_fma_mix_f32 (f32 accumulate,
    // no separate v_cvt).
    auto gat = [&](const vuint3& q, float wt) {
        const unsigned int qx = q.x, qy = q.y, qz = q.z;
        const __half2 h01 = *reinterpret_cast<const __half2*>(&qx);
        const __half2 h23 = *reinterpret_cast<const __half2*>(&qy);
        const __half2 h45 = *reinterpret_cast<const __half2*>(&qz);
        acc0 = fmaf(__half2float(__low2half(h01)), wt, acc0);
        acc1 = fmaf(__half2float(__high2half(h01)), wt, acc1);
        acc2 = fmaf(__half2float(__low2half(h23)), wt, acc2);
        acc3 = fmaf(__half2float(__high2half(h23)), wt, acc3);
        acc4 = fmaf(__half2float(__low2half(h45)), wt, acc4);
        acc5 = fmaf(__half2float(__high2half(h45)), wt, acc5);
    };

    gat(q0, gx0 * gy0 * gz0);
    gat(q1, gx0 * gy0 * fz);
    gat(q2, gx0 * fy * gz0);
    gat(q3, gx0 * fy * fz);
    gat(q4, fx * gy0 * gz0);
    gat(q5, fx * gy0 * fz);
    gat(q6, fx * fy * gz0);
    gat(q7, fx * fy * fz);

    // ---- rare ill-conditioned fallback (gather regs dead by now) ----
    if (__builtin_expect(bad, 0)) polar_f64(J, X);

    // ---- Dp = R^T M R ----
    const float M00 = acc0, M01 = acc1, M11 = acc2;
    const float M02 = acc3, M12 = acc4, M22 = acc5;
    float P[9];  // P = M * R
    P[0] = M00 * X[0] + M01 * X[3] + M02 * X[6];
    P[1] = M00 * X[1] + M01 * X[4] + M02 * X[7];
    P[2] = M00 * X[2] + M01 * X[5] + M02 * X[8];
    P[3] = M01 * X[0] + M11 * X[3] + M12 * X[6];
    P[4] = M01 * X[1] + M11 * X[4] + M12 * X[7];
    P[5] = M01 * X[2] + M11 * X[5] + M12 * X[8];
    P[6] = M02 * X[0] + M12 * X[3] + M22 * X[6];
    P[7] = M02 * X[1] + M12 * X[4] + M22 * X[7];
    P[8] = M02 * X[2] + M12 * X[5] + M22 * X[8];

    // Output: 48 MB, zero reuse -> non-temporal so it doesn't evict aos
    // from L2/L3 between gathers.
    __builtin_nontemporal_store(X[0] * P[0] + X[3] * P[3] + X[6] * P[6], &out[0 * NVOX + id]);
    __builtin_nontemporal_store(X[1] * P[0] + X[4] * P[3] + X[7] * P[6], &out[1 * NVOX + id]);
    __builtin_nontemporal_store(X[1] * P[1] + X[4] * P[4] + X[7] * P[7], &out[2 * NVOX + id]);
    __builtin_nontemporal_store(X[2] * P[0] + X[5] * P[3] + X[8] * P[6], &out[3 * NVOX + id]);
    __builtin_nontemporal_store(X[2] * P[1] + X[5] * P[4] + X[8] * P[7], &out[4 * NVOX + id]);
    __builtin_nontemporal_store(X[2] * P[2] + X[5] * P[5] + X[8] * P[8], &out[5 * NVOX + id]);
}

extern "C" void kernel_launch(void* const* d_in, const int* in_sizes, int n_in,
                              void* d_out, int out_size, void* d_ws, size_t ws_size,
                              hipStream_t stream) {
    const float* dti = (const float*)d_in[0];
    const float* ddf = (const float*)d_in[1];
    float* out = (float*)d_out;
    vuint4* aos = (vuint4*)d_ws;  // 2M voxels * 16 B = 32 MB scratch

    hipLaunchKernelGGL(pack_dti_kernel, dim3(NVOX / 1024), dim3(256), 0, stream,
                       dti, aos);
    hipLaunchKernelGGL(warp_dti_kernel, dim3(NVOX / 256), dim3(256), 0, stream,
                       (const vuint3*)aos, ddf, out);
}